// Round 11
// baseline (74.564 us; speedup 1.0000x reference)
//
#include <hip/hip_runtime.h>
#include <hip/hip_bf16.h>

#define NMOV 32768
#define LW 15
#define DIM 256
#define NVOC 27
#define NR 405       // NVOC * LW distinct (letter, position) rows
#define GSH 408      // row stride of H in float2 units
#define MPB 16       // moves per block in moves_kernel

__device__ __forceinline__ float b2f(unsigned short u) {
    return __uint_as_float(((unsigned int)u) << 16);
}
__device__ __forceinline__ unsigned short f2bu(float x) {
    __hip_bfloat16 h = __float2bfloat16(x);
    return *reinterpret_cast<unsigned short*>(&h);
}

// pair index p -> (l<<4 | m), l >= m, p = l(l+1)/2 + m
__device__ const unsigned char PAIR_LUT[120] = {
    0x00,
    0x10,0x11,
    0x20,0x21,0x22,
    0x30,0x31,0x32,0x33,
    0x40,0x41,0x42,0x43,0x44,
    0x50,0x51,0x52,0x53,0x54,0x55,
    0x60,0x61,0x62,0x63,0x64,0x65,0x66,
    0x70,0x71,0x72,0x73,0x74,0x75,0x76,0x77,
    0x80,0x81,0x82,0x83,0x84,0x85,0x86,0x87,0x88,
    0x90,0x91,0x92,0x93,0x94,0x95,0x96,0x97,0x98,0x99,
    0xA0,0xA1,0xA2,0xA3,0xA4,0xA5,0xA6,0xA7,0xA8,0xA9,0xAA,
    0xB0,0xB1,0xB2,0xB3,0xB4,0xB5,0xB6,0xB7,0xB8,0xB9,0xBA,0xBB,
    0xC0,0xC1,0xC2,0xC3,0xC4,0xC5,0xC6,0xC7,0xC8,0xC9,0xCA,0xCB,0xCC,
    0xD0,0xD1,0xD2,0xD3,0xD4,0xD5,0xD6,0xD7,0xD8,0xD9,0xDA,0xDB,0xDC,0xDD,
    0xE0,0xE1,0xE2,0xE3,0xE4,0xE5,0xE6,0xE7,0xE8,0xE9,0xEA,0xEB,0xEC,0xED,0xEE
};

// ---------------------------------------------------------------------------
// Kernel 1 v5: QKV GEMM with SPLIT-K=2 (f32 atomic accumulate; buffers
// zeroed each call by hipMemsetAsync). Blocks [0,624): gb=b>>1 selects the
// 32x32 tile (13 row-tiles x 24 col-tiles), kh=b&1 selects K half (128).
// kh==0 adds the bias. Each (r,c,kh) is written by exactly one block.
// Blocks [624,657): convert the 4 epilogue tables to bf16 EPI[132][256].
// ---------------------------------------------------------------------------
__global__ __launch_bounds__(256) void qkv_gemm(
    const float* __restrict__ le, const float* __restrict__ pos,
    const float* __restrict__ Wq, const float* __restrict__ bq,
    const float* __restrict__ Wk, const float* __restrict__ bk,
    const float* __restrict__ Wv, const float* __restrict__ bv,
    const float* __restrict__ row_emb, const float* __restrict__ col_emb,
    const float* __restrict__ dir_emb, const float* __restrict__ score_emb,
    float* __restrict__ QT, float* __restrict__ KT,
    float* __restrict__ VTF, __hip_bfloat16* __restrict__ EPI)
{
    const int t = threadIdx.x;
    if (blockIdx.x >= 624) {
        // ---- EPI conversion: 33 blocks x 1024 floats = 33792 = 132*256
        int idx = (blockIdx.x - 624) * 1024 + t * 4;
        float4 v;
        if (idx < 15 * 256)       v = *(const float4*)&row_emb[idx];
        else if (idx < 30 * 256)  v = *(const float4*)&col_emb[idx - 15 * 256];
        else if (idx < 32 * 256)  v = *(const float4*)&dir_emb[idx - 30 * 256];
        else                      v = *(const float4*)&score_emb[idx - 32 * 256];
        ushort4 o;
        o.x = f2bu(v.x); o.y = f2bu(v.y); o.z = f2bu(v.z); o.w = f2bu(v.w);
        *(ushort4*)((unsigned short*)EPI + idx) = o;
        return;
    }

    __shared__ float Ash[32][68];
    __shared__ float Bsh[32][68];
    const int gb = blockIdx.x >> 1;
    const int kh = blockIdx.x & 1;
    const int koff = kh * 128;
    const int bx = gb % 24;
    const int by = gb / 24;
    const int r0 = by * 32;
    const int mat = bx >> 3;             // 0=Q 1=K 2=V
    const int nb  = (bx & 7) * 32;       // col base within mat
    const float* W  = (mat == 0) ? Wq : (mat == 1) ? Wk : Wv;
    const float* bb = (mat == 0) ? bq : (mat == 1) ? bk : bv;

    const int ti = t >> 4, tj = t & 15;
    float acc00 = 0.f, acc01 = 0.f, acc10 = 0.f, acc11 = 0.f;

    for (int k0 = koff; k0 < koff + 128; k0 += 64) {
        #pragma unroll
        for (int s = 0; s < 2; ++s) {
            int slot = s * 256 + t;      // 512 float4 slots per tile
            int row = slot >> 4, c4 = slot & 15;
            int r = r0 + row;
            float4 va = make_float4(0.f, 0.f, 0.f, 0.f);
            if (r < NR) {
                int c = r / 15, l = r - c * 15;
                float4 lv = *(const float4*)&le[c * DIM + k0 + c4 * 4];
                float4 pv = *(const float4*)&pos[l * DIM + k0 + c4 * 4];
                va = make_float4(lv.x + pv.x, lv.y + pv.y, lv.z + pv.z, lv.w + pv.w);
            }
            *(float4*)&Ash[row][c4 * 4] = va;
            float4 vb = *(const float4*)&W[(nb + row) * DIM + k0 + c4 * 4];
            *(float4*)&Bsh[row][c4 * 4] = vb;
        }
        __syncthreads();
        #pragma unroll 4
        for (int kk = 0; kk < 64; kk += 4) {
            float4 a0 = *(const float4*)&Ash[2 * ti][kk];
            float4 a1 = *(const float4*)&Ash[2 * ti + 1][kk];
            float4 b0 = *(const float4*)&Bsh[tj][kk];
            float4 b1 = *(const float4*)&Bsh[tj + 16][kk];
            acc00 += a0.x * b0.x + a0.y * b0.y + a0.z * b0.z + a0.w * b0.w;
            acc01 += a0.x * b1.x + a0.y * b1.y + a0.z * b1.z + a0.w * b1.w;
            acc10 += a1.x * b0.x + a1.y * b0.y + a1.z * b0.z + a1.w * b0.w;
            acc11 += a1.x * b1.x + a1.y * b1.y + a1.z * b1.z + a1.w * b1.w;
        }
        __syncthreads();
    }

    const int c0 = nb + tj, c1 = nb + tj + 16;
    const float bias0 = (kh == 0) ? bb[c0] : 0.f;
    const float bias1 = (kh == 0) ? bb[c1] : 0.f;
    float* D = (mat == 0) ? QT : (mat == 1) ? KT : VTF;
    #pragma unroll
    for (int rr = 0; rr < 2; ++rr) {
        int r = r0 + 2 * ti + rr;
        if (r < NR) {
            float v0 = (rr == 0 ? acc00 : acc10) + bias0;
            float v1 = (rr == 0 ? acc01 : acc11) + bias1;
            atomicAdd(&D[r * DIM + c0], v0);
            atomicAdd(&D[r * DIM + c1], v1);
        }
    }
}

// ---------------------------------------------------------------------------
// Kernel 2 v3: H with SPLIT-K=2 (f32 atomic accumulate into zeroed H).
// gb = b>>1 selects the tile-pair (351), kh = b&1 selects the K half.
// BUGFIX vs R10: for DIAGONAL tile-pairs (bi==bj) the (i2,j2) write set is
// identical to (i1,j1) — with idempotent stores that was harmless, with
// atomicAdd it double-counted. Guard the second write with bi != bj.
// ---------------------------------------------------------------------------
__global__ __launch_bounds__(256) void h_matrix(
    const float* __restrict__ QT, const float* __restrict__ KT,
    float2* __restrict__ H)
{
    __shared__ float Qi[16][68], Ki[16][68], Qj[16][68], Kj[16][68];

    const int gb = blockIdx.x >> 1;
    const int kh = blockIdx.x & 1;
    const int koff = kh * 128;
    int rem = gb, bi = 0, cnt = 26;
    while (rem >= cnt) { rem -= cnt; ++bi; --cnt; }
    const int bj = bi + rem;
    const int i0 = bi * 16, j0 = bj * 16;
    const int t = threadIdx.x;
    const int ti = t >> 4, tj = t & 15;

    float acc_ij = 0.f, acc_ji = 0.f;

    for (int k0 = koff; k0 < koff + 128; k0 += 64) {
        #pragma unroll
        for (int s = 0; s < 4; ++s) {
            int slot = s * 256 + t;
            int tile = slot >> 8;
            int r    = (slot >> 4) & 15;
            int c4   = slot & 15;
            int grow = (tile < 2) ? (i0 + r) : (j0 + r);
            const float* src = (tile == 0 || tile == 2) ? QT : KT;
            float4 v = (grow < NR)
                ? *(const float4*)&src[grow * DIM + k0 + c4 * 4]
                : make_float4(0.f, 0.f, 0.f, 0.f);
            float* dst = (tile == 0) ? &Qi[r][c4 * 4]
                       : (tile == 1) ? &Ki[r][c4 * 4]
                       : (tile == 2) ? &Qj[r][c4 * 4] : &Kj[r][c4 * 4];
            *(float4*)dst = v;
        }
        __syncthreads();
        #pragma unroll 4
        for (int k = 0; k < 64; k += 4) {
            float4 qi = *(const float4*)&Qi[ti][k];
            float4 kj = *(const float4*)&Kj[tj][k];
            float4 qj = *(const float4*)&Qj[ti][k];
            float4 ki = *(const float4*)&Ki[tj][k];
            acc_ij += qi.x * kj.x + qi.y * kj.y + qi.z * kj.z + qi.w * kj.w;
            acc_ji += qj.x * ki.x + qj.y * ki.y + qj.z * ki.z + qj.w * ki.w;
        }
        __syncthreads();
    }

    Qi[ti][tj] = acc_ij;
    Ki[ti][tj] = acc_ji;
    __syncthreads();
    const float t_ij = Qi[tj][ti];   // G[i0+tj][j0+ti] partial
    const float t_ji = Ki[tj][ti];   // G[j0+tj][i0+ti] partial

    const int i1 = i0 + ti, j1 = j0 + tj;
    if (i1 < NR && j1 < NR) {
        float* p = (float*)&H[i1 * GSH + j1];
        atomicAdd(p + 0, acc_ij);
        atomicAdd(p + 1, t_ji);
    }
    if (bi != bj) {                  // diagonal pairs: second set == first set
        const int i2 = j0 + ti, j2 = i0 + tj;
        if (i2 < NR && j2 < NR) {
            float* p = (float*)&H[i2 * GSH + j2];
            atomicAdd(p + 0, acc_ji);
            atomicAdd(p + 1, t_ij);
        }
    }
}

// ---------------------------------------------------------------------------
// Kernel 3: wave-synchronous per-move pipeline, ZERO __syncthreads.
// (identical to R10: f32 V table, direct word loads, bf16 EPI epilogue)
// NOTE: __launch_bounds__(256) ONLY — a min-waves arg spills to scratch (R4).
// ---------------------------------------------------------------------------
__global__ __launch_bounds__(256) void moves_kernel(
    const int* __restrict__ words, const int* __restrict__ rowsI,
    const int* __restrict__ colsI, const int* __restrict__ dirsI,
    const int* __restrict__ scoresI,
    const float2* __restrict__ H, const float* __restrict__ VTF,
    const __hip_bfloat16* __restrict__ EPI,
    float* __restrict__ out)
{
    __shared__ float S[MPB][LW][17];     // 15x15 score matrix per move (padded)
    __shared__ int   rIdx[MPB][16];      // row indices per move (for phase 2)
    __shared__ float csum[MPB][16];      // per-move column sums
    __shared__ int   meta[MPB][4];       // EPI row indices per move
    const int base = blockIdx.x * MPB;
    const int t  = threadIdx.x;
    const int w  = t >> 6;               // wave id: owns moves 4w..4w+3
    const int ln = t & 63;
    const int hw = t >> 5;               // half-wave: owns moves 2hw, 2hw+1
    const int j  = t & 31;

    // -------- phase 1: direct word-index loads (independent, issue at once)
    const int mv0 = hw * 2, mv1 = mv0 + 1;
    const int* w0 = words + (base + mv0) * LW;
    const int* w1 = words + (base + mv1) * LW;
    int ll[4], mm[4];
    float2 h0[4], h1[4];
    #pragma unroll
    for (int k = 0; k < 4; ++k) {
        int p = j + 32 * k;
        if (p < 120) {
            int lm = PAIR_LUT[p];
            ll[k] = lm >> 4; mm[k] = lm & 15;
            int rl0 = w0[ll[k]] * LW + ll[k];
            int rm0 = w0[mm[k]] * LW + mm[k];
            int rl1 = w1[ll[k]] * LW + ll[k];
            int rm1 = w1[mm[k]] * LW + mm[k];
            h0[k] = H[(size_t)rl0 * GSH + rm0];
            h1[k] = H[(size_t)rl1 * GSH + rm1];
        }
    }

    // concurrent: rIdx + meta staged for phase 2 (same wave writes & reads)
    if (ln < 60) {
        int mvl = ln / 15, row = ln - mvl * 15;
        int mv = w * 4 + mvl;
        rIdx[mv][row] = words[(base + mv) * LW + row] * LW + row;
    }
    if (ln < 16) {
        int mvl = ln >> 2, f = ln & 3;
        int n = base + w * 4 + mvl;
        int v = (f == 0) ? rowsI[n] : (f == 1) ? 15 + colsI[n]
              : (f == 2) ? 30 + dirsI[n] : 32 + min(scoresI[n], 99);
        meta[w * 4 + mvl][f] = v;
    }

    // scatter gather results into S
    #pragma unroll
    for (int k = 0; k < 4; ++k) {
        int p = j + 32 * k;
        if (p < 120) {
            S[mv0][ll[k]][mm[k]] = h0[k].x;
            S[mv0][mm[k]][ll[k]] = h0[k].y;
            S[mv1][ll[k]][mm[k]] = h1[k].x;
            S[mv1][mm[k]][ll[k]] = h1[k].y;
        }
    }
    __builtin_amdgcn_wave_barrier();

    // -------- row softmax: lane ln<60 -> (move w*4 + ln/15, row ln%15)
    if (ln < 60) {
        int mvl = ln / 15, row = ln - mvl * 15;
        int mv = w * 4 + mvl;
        float s[LW];
        #pragma unroll
        for (int m = 0; m < LW; ++m) s[m] = S[mv][row][m];
        float mx = s[0];
        #pragma unroll
        for (int m = 1; m < LW; ++m) mx = fmaxf(mx, s[m]);
        float sum = 0.f;
        #pragma unroll
        for (int m = 0; m < LW; ++m) { s[m] = __expf(s[m] - mx); sum += s[m]; }
        float inv = 1.0f / sum;
        #pragma unroll
        for (int m = 0; m < LW; ++m) S[mv][row][m] = s[m] * inv;
    }
    __builtin_amdgcn_wave_barrier();

    // -------- column sums: lane ln<60 -> (move, column)
    if (ln < 60) {
        int mvl = ln / 15, col = ln - mvl * 15;
        int mv = w * 4 + mvl;
        float acc = 0.f;
        #pragma unroll
        for (int l = 0; l < LW; ++l) acc += S[mv][l][col];
        csum[mv][col] = acc;
    }
    __builtin_amdgcn_wave_barrier();

    // -------- phase 2: wave w handles moves 4w..4w+3
    const int d0 = ln * 4;
    const unsigned short* EP16 = (const unsigned short*)EPI;
    #pragma unroll 1
    for (int s2 = 0; s2 < 4; ++s2) {
        const int i = w * 4 + s2;
        const int n = base + i;
        // batch 1: 4 bf16 epilogue rows + first 8 V rows (f32)
        ushort4 re = *(const ushort4*)(EP16 + meta[i][0] * DIM + d0);
        ushort4 ce = *(const ushort4*)(EP16 + meta[i][1] * DIM + d0);
        ushort4 de = *(const ushort4*)(EP16 + meta[i][2] * DIM + d0);
        ushort4 se = *(const ushort4*)(EP16 + meta[i][3] * DIM + d0);
        float4 va[8];
        #pragma unroll
        for (int m = 0; m < 8; ++m)
            va[m] = *(const float4*)(VTF + (size_t)rIdx[i][m] * DIM + d0);
        float wx = 0.f, wy = 0.f, wz = 0.f, ww = 0.f;
        #pragma unroll
        for (int m = 0; m < 8; ++m) {
            float c = csum[i][m];
            wx += c * va[m].x; wy += c * va[m].y;
            wz += c * va[m].z; ww += c * va[m].w;
        }
        // batch 2: remaining 7 V rows
        float4 vb[7];
        #pragma unroll
        for (int m = 0; m < 7; ++m)
            vb[m] = *(const float4*)(VTF + (size_t)rIdx[i][8 + m] * DIM + d0);
        #pragma unroll
        for (int m = 0; m < 7; ++m) {
            float c = csum[i][8 + m];
            wx += c * vb[m].x; wy += c * vb[m].y;
            wz += c * vb[m].z; ww += c * vb[m].w;
        }
        float4 res;
        res.x = 2.f * wx + b2f(re.x) + b2f(ce.x) + b2f(de.x) + b2f(se.x);
        res.y = 2.f * wy + b2f(re.y) + b2f(ce.y) + b2f(de.y) + b2f(se.y);
        res.z = 2.f * wz + b2f(re.z) + b2f(ce.z) + b2f(de.z) + b2f(se.z);
        res.w = 2.f * ww + b2f(re.w) + b2f(ce.w) + b2f(de.w) + b2f(se.w);
        *(float4*)&out[(size_t)n * DIM + d0] = res;
    }
}

extern "C" void kernel_launch(void* const* d_in, const int* in_sizes, int n_in,
                              void* d_out, int out_size, void* d_ws, size_t ws_size,
                              hipStream_t stream)
{
    const int*   words      = (const int*)d_in[0];
    const int*   rowsI      = (const int*)d_in[1];
    const int*   colsI      = (const int*)d_in[2];
    const int*   dirsI      = (const int*)d_in[3];
    const int*   scoresI    = (const int*)d_in[4];
    const float* letter_emb = (const float*)d_in[5];
    const float* positional = (const float*)d_in[6];
    const float* Wq         = (const float*)d_in[7];
    const float* bq         = (const float*)d_in[8];
    const float* Wk         = (const float*)d_in[9];
    const float* bk         = (const float*)d_in[10];
    const float* Wv         = (const float*)d_in[11];
    const float* bv         = (const float*)d_in[12];
    const float* row_emb    = (const float*)d_in[13];
    const float* col_emb    = (const float*)d_in[14];
    const float* dir_emb    = (const float*)d_in[15];
    const float* score_emb  = (const float*)d_in[16];
    float* out = (float*)d_out;

    // workspace: QT f32[103680] | KT f32[103680] | H f2[405*408] | VTF f32[103680] | EPI bf16[33792]
    float*  QT  = (float*)d_ws;
    float*  KT  = QT + NR * DIM;
    float2* Hm  = (float2*)(KT + NR * DIM);
    float*  VTF = (float*)((char*)Hm + (size_t)NR * GSH * sizeof(float2));
    __hip_bfloat16* EPI = (__hip_bfloat16*)(VTF + NR * DIM);

    // zero the atomic-accumulated region each call (QT|KT|H|VTF contiguous):
    // required for determinism across graph replays.
    size_t zero_bytes = (size_t)(2 * NR * DIM * 4) + (size_t)NR * GSH * 8
                      + (size_t)NR * DIM * 4;
    hipMemsetAsync(d_ws, 0, zero_bytes, stream);

    qkv_gemm<<<657, 256, 0, stream>>>(letter_emb, positional, Wq, bq, Wk, bk,
                                      Wv, bv, row_emb, col_emb, dir_emb,
                                      score_emb, QT, KT, VTF, EPI);
    h_matrix<<<702, 256, 0, stream>>>(QT, KT, Hm);
    moves_kernel<<<NMOV / MPB, 256, 0, stream>>>(words, rowsI, colsI, dirsI,
                                                 scoresI, Hm, VTF, EPI, out);
}

// Round 12
// 60.556 us; speedup vs baseline: 1.2313x; 1.2313x over previous
//
#include <hip/hip_runtime.h>
#include <hip/hip_bf16.h>

#define NMOV 32768
#define LW 15
#define DIM 256
#define NVOC 27
#define NR 405       // NVOC * LW distinct (letter, position) rows
#define GSH 408      // row stride of H in float2 units
#define MPB 16       // moves per block in moves_kernel
#define NEP 550      // EP2 rows: 450 vec combos + 100 score rows

__device__ __forceinline__ float b2f(unsigned short u) {
    return __uint_as_float(((unsigned int)u) << 16);
}
__device__ __forceinline__ unsigned short f2bu(float x) {
    __hip_bfloat16 h = __float2bfloat16(x);
    return *reinterpret_cast<unsigned short*>(&h);
}

// pair index p -> (l<<4 | m), l >= m, p = l(l+1)/2 + m
__device__ const unsigned char PAIR_LUT[120] = {
    0x00,
    0x10,0x11,
    0x20,0x21,0x22,
    0x30,0x31,0x32,0x33,
    0x40,0x41,0x42,0x43,0x44,
    0x50,0x51,0x52,0x53,0x54,0x55,
    0x60,0x61,0x62,0x63,0x64,0x65,0x66,
    0x70,0x71,0x72,0x73,0x74,0x75,0x76,0x77,
    0x80,0x81,0x82,0x83,0x84,0x85,0x86,0x87,0x88,
    0x90,0x91,0x92,0x93,0x94,0x95,0x96,0x97,0x98,0x99,
    0xA0,0xA1,0xA2,0xA3,0xA4,0xA5,0xA6,0xA7,0xA8,0xA9,0xAA,
    0xB0,0xB1,0xB2,0xB3,0xB4,0xB5,0xB6,0xB7,0xB8,0xB9,0xBA,0xBB,
    0xC0,0xC1,0xC2,0xC3,0xC4,0xC5,0xC6,0xC7,0xC8,0xC9,0xCA,0xCB,0xCC,
    0xD0,0xD1,0xD2,0xD3,0xD4,0xD5,0xD6,0xD7,0xD8,0xD9,0xDA,0xDB,0xDC,0xDD,
    0xE0,0xE1,0xE2,0xE3,0xE4,0xE5,0xE6,0xE7,0xE8,0xE9,0xEA,0xEB,0xEC,0xED,0xEE
};

// ---------------------------------------------------------------------------
// Kernel 1 (R8-proven v3 + EP2 builder): 16x16-tile QKV GEMM, full K in LDS.
// Blocks [0,1248): by = 16-row tile of emb (26), bx = 16-col tile (48).
// Blocks [1248,1386): build EP2[550][256] bf16 — rows 0-449:
// row_emb[r]+col_emb[c]+dir_emb[d] (v = r*30+c*2+d), rows 450-549: score_emb.
// ---------------------------------------------------------------------------
__global__ __launch_bounds__(256) void qkv_gemm(
    const float* __restrict__ le, const float* __restrict__ pos,
    const float* __restrict__ Wq, const float* __restrict__ bq,
    const float* __restrict__ Wk, const float* __restrict__ bk,
    const float* __restrict__ Wv, const float* __restrict__ bv,
    const float* __restrict__ row_emb, const float* __restrict__ col_emb,
    const float* __restrict__ dir_emb, const float* __restrict__ score_emb,
    float* __restrict__ QT, float* __restrict__ KT,
    __hip_bfloat16* __restrict__ VT, __hip_bfloat16* __restrict__ EP2)
{
    const int t = threadIdx.x;
    if (blockIdx.x >= 1248) {
        int idx = (blockIdx.x - 1248) * 1024 + t * 4;   // 4 elems, same row
        if (idx < NEP * DIM) {
            int v = idx >> 8, dcol = idx & 255;
            float4 s4;
            if (v < 450) {
                int r = v / 30, rm = v % 30, c = rm >> 1, d = rm & 1;
                float4 a = *(const float4*)&row_emb[r * DIM + dcol];
                float4 b = *(const float4*)&col_emb[c * DIM + dcol];
                float4 e = *(const float4*)&dir_emb[d * DIM + dcol];
                s4 = make_float4(a.x + b.x + e.x, a.y + b.y + e.y,
                                 a.z + b.z + e.z, a.w + b.w + e.w);
            } else {
                s4 = *(const float4*)&score_emb[(v - 450) * DIM + dcol];
            }
            ushort4 o;
            o.x = f2bu(s4.x); o.y = f2bu(s4.y);
            o.z = f2bu(s4.z); o.w = f2bu(s4.w);
            *(ushort4*)((unsigned short*)EP2 + idx) = o;
        }
        return;
    }

    __shared__ float Ash[16][260];
    __shared__ float Bsh[16][260];
    const int bx = blockIdx.x % 48;
    const int by = blockIdx.x / 48;
    const int r0 = by * 16;
    const int mat = bx >> 4;             // 0=Q 1=K 2=V
    const int nb  = (bx & 15) * 16;      // col base within mat
    const float* W  = (mat == 0) ? Wq : (mat == 1) ? Wk : Wv;
    const float* bb = (mat == 0) ? bq : (mat == 1) ? bk : bv;

    #pragma unroll
    for (int s = 0; s < 4; ++s) {
        int slot = s * 256 + t;          // 1024 float4 slots per tile
        int row = slot >> 6, q4 = slot & 63;
        int r = r0 + row;
        float4 va = make_float4(0.f, 0.f, 0.f, 0.f);
        if (r < NR) {
            int c = r / 15, l = r - c * 15;
            float4 lv = *(const float4*)&le[c * DIM + q4 * 4];
            float4 pv = *(const float4*)&pos[l * DIM + q4 * 4];
            va = make_float4(lv.x + pv.x, lv.y + pv.y, lv.z + pv.z, lv.w + pv.w);
        }
        *(float4*)&Ash[row][q4 * 4] = va;
        float4 vb = *(const float4*)&W[(nb + row) * DIM + q4 * 4];
        *(float4*)&Bsh[row][q4 * 4] = vb;
    }
    __syncthreads();

    const int tj = t & 15, ti = t >> 4;
    float acc = 0.f;
    #pragma unroll 8
    for (int k = 0; k < DIM; k += 4) {
        float4 a = *(const float4*)&Ash[ti][k];
        float4 b = *(const float4*)&Bsh[tj][k];
        acc += a.x * b.x + a.y * b.y + a.z * b.z + a.w * b.w;
    }

    const int r = r0 + ti;
    if (r < NR) {
        float v = acc + bb[nb + tj];
        int dcol = nb + tj;
        if (mat == 0)      QT[r * DIM + dcol] = v;
        else if (mat == 1) KT[r * DIM + dcol] = v;
        else               VT[r * DIM + dcol] = __float2bfloat16(v);
    }
}

// ---------------------------------------------------------------------------
// Kernel 2: H[i][j] = { G[i][j], G[j][i] } — R8-proven version (plain stores;
// diagonal-pair double write is idempotent).
// ---------------------------------------------------------------------------
__global__ __launch_bounds__(256) void h_matrix(
    const float* __restrict__ QT, const float* __restrict__ KT,
    float2* __restrict__ H)
{
    __shared__ float Qi[16][68], Ki[16][68], Qj[16][68], Kj[16][68];

    int rem = blockIdx.x, bi = 0, cnt = 26;
    while (rem >= cnt) { rem -= cnt; ++bi; --cnt; }
    const int bj = bi + rem;
    const int i0 = bi * 16, j0 = bj * 16;
    const int t = threadIdx.x;
    const int ti = t >> 4, tj = t & 15;

    float acc_ij = 0.f, acc_ji = 0.f;

    for (int k0 = 0; k0 < DIM; k0 += 64) {
        #pragma unroll
        for (int s = 0; s < 4; ++s) {
            int slot = s * 256 + t;
            int tile = slot >> 8;
            int r    = (slot >> 4) & 15;
            int c4   = slot & 15;
            int grow = (tile < 2) ? (i0 + r) : (j0 + r);
            const float* src = (tile == 0 || tile == 2) ? QT : KT;
            float4 v = (grow < NR)
                ? *(const float4*)&src[grow * DIM + k0 + c4 * 4]
                : make_float4(0.f, 0.f, 0.f, 0.f);
            float* dst = (tile == 0) ? &Qi[r][c4 * 4]
                       : (tile == 1) ? &Ki[r][c4 * 4]
                       : (tile == 2) ? &Qj[r][c4 * 4] : &Kj[r][c4 * 4];
            *(float4*)dst = v;
        }
        __syncthreads();
        #pragma unroll 4
        for (int k = 0; k < 64; k += 4) {
            float4 qi = *(const float4*)&Qi[ti][k];
            float4 kj = *(const float4*)&Kj[tj][k];
            float4 qj = *(const float4*)&Qj[ti][k];
            float4 ki = *(const float4*)&Ki[tj][k];
            acc_ij += qi.x * kj.x + qi.y * kj.y + qi.z * kj.z + qi.w * kj.w;
            acc_ji += qj.x * ki.x + qj.y * ki.y + qj.z * ki.z + qj.w * ki.w;
        }
        __syncthreads();
    }

    Qi[ti][tj] = acc_ij;
    Ki[ti][tj] = acc_ji;
    __syncthreads();
    const float t_ij = Qi[tj][ti];
    const float t_ji = Ki[tj][ti];

    const int i1 = i0 + ti, j1 = j0 + tj;
    if (i1 < NR && j1 < NR) H[i1 * GSH + j1] = make_float2(acc_ij, t_ji);
    const int i2 = j0 + ti, j2 = i0 + tj;
    if (i2 < NR && j2 < NR) H[i2 * GSH + j2] = make_float2(acc_ji, t_ij);
}

// ---------------------------------------------------------------------------
// Kernel 3 (R8 base + EP2 epilogue): wave-synchronous, ZERO __syncthreads.
// bf16 VT + ushort4 batches keep VGPR ~36 (the 64-VGPR cliff halves occupancy
// — R11 lesson). Epilogue = 2 bf16 EP2 rows (16 lines/move vs 64 for f32x4).
// NOTE: __launch_bounds__(256) ONLY — a min-waves arg spills to scratch (R4).
// ---------------------------------------------------------------------------
__global__ __launch_bounds__(256) void moves_kernel(
    const int* __restrict__ words, const int* __restrict__ rowsI,
    const int* __restrict__ colsI, const int* __restrict__ dirsI,
    const int* __restrict__ scoresI,
    const float2* __restrict__ H, const __hip_bfloat16* __restrict__ VT,
    const __hip_bfloat16* __restrict__ EP2,
    float* __restrict__ out)
{
    __shared__ float S[MPB][LW][17];     // 15x15 score matrix per move (padded)
    __shared__ int   rIdx[MPB][16];      // row indices per move
    __shared__ float csum[MPB][16];      // per-move column sums
    __shared__ int   meta[MPB][2];       // EP2 row indices: vec, score
    const int base = blockIdx.x * MPB;
    const int t  = threadIdx.x;
    const int w  = t >> 6;               // wave id: owns moves 4w..4w+3
    const int ln = t & 63;
    const int hw = t >> 5;               // half-wave: owns moves 2hw, 2hw+1
    const int j  = t & 31;

    // rIdx + meta loaded by the OWNING wave's lanes (wave-local LDS)
    if (ln < 60) {
        int mvl = ln / 15, row = ln - mvl * 15;
        int mv = w * 4 + mvl;
        rIdx[mv][row] = words[(base + mv) * LW + row] * LW + row;
    }
    if (ln < 8) {
        int mvl = ln >> 1, f = ln & 1;
        int n = base + w * 4 + mvl;
        int v = (f == 0) ? (rowsI[n] * 30 + colsI[n] * 2 + dirsI[n])
                         : (450 + min(scoresI[n], 99));
        meta[w * 4 + mvl][f] = v;
    }
    __builtin_amdgcn_wave_barrier();

    // -------- phase 1: 8 H-gathers in flight per wave (2 moves x 4 pairs)
    const int mv0 = hw * 2, mv1 = mv0 + 1;
    float2 h0[4], h1[4];
    int ll[4], mm[4];
    #pragma unroll
    for (int k = 0; k < 4; ++k) {
        int p = j + 32 * k;
        if (p < 120) {
            int lm = PAIR_LUT[p];
            ll[k] = lm >> 4; mm[k] = lm & 15;
            h0[k] = H[(size_t)rIdx[mv0][ll[k]] * GSH + rIdx[mv0][mm[k]]];
            h1[k] = H[(size_t)rIdx[mv1][ll[k]] * GSH + rIdx[mv1][mm[k]]];
        }
    }
    #pragma unroll
    for (int k = 0; k < 4; ++k) {
        int p = j + 32 * k;
        if (p < 120) {
            S[mv0][ll[k]][mm[k]] = h0[k].x;
            S[mv0][mm[k]][ll[k]] = h0[k].y;
            S[mv1][ll[k]][mm[k]] = h1[k].x;
            S[mv1][mm[k]][ll[k]] = h1[k].y;
        }
    }
    __builtin_amdgcn_wave_barrier();

    // -------- row softmax: lane ln<60 -> (move w*4 + ln/15, row ln%15)
    if (ln < 60) {
        int mvl = ln / 15, row = ln - mvl * 15;
        int mv = w * 4 + mvl;
        float s[LW];
        #pragma unroll
        for (int m = 0; m < LW; ++m) s[m] = S[mv][row][m];
        float mx = s[0];
        #pragma unroll
        for (int m = 1; m < LW; ++m) mx = fmaxf(mx, s[m]);
        float sum = 0.f;
        #pragma unroll
        for (int m = 0; m < LW; ++m) { s[m] = __expf(s[m] - mx); sum += s[m]; }
        float inv = 1.0f / sum;
        #pragma unroll
        for (int m = 0; m < LW; ++m) S[mv][row][m] = s[m] * inv;
    }
    __builtin_amdgcn_wave_barrier();

    // -------- column sums: lane ln<60 -> (move, column)
    if (ln < 60) {
        int mvl = ln / 15, col = ln - mvl * 15;
        int mv = w * 4 + mvl;
        float acc = 0.f;
        #pragma unroll
        for (int l = 0; l < LW; ++l) acc += S[mv][l][col];
        csum[mv][col] = acc;
    }
    __builtin_amdgcn_wave_barrier();

    // -------- phase 2: wave w handles moves 4w..4w+3
    const int d0 = ln * 4;
    const unsigned short* VT16 = (const unsigned short*)VT;
    const unsigned short* EP16 = (const unsigned short*)EP2;
    #pragma unroll 1
    for (int s2 = 0; s2 < 4; ++s2) {
        const int i = w * 4 + s2;
        const int n = base + i;
        // batch 1: 2 bf16 epilogue rows + first 8 VT rows
        ushort4 ve = *(const ushort4*)(EP16 + meta[i][0] * DIM + d0);
        ushort4 se = *(const ushort4*)(EP16 + meta[i][1] * DIM + d0);
        ushort4 va[8];
        #pragma unroll
        for (int m = 0; m < 8; ++m)
            va[m] = *(const ushort4*)(VT16 + (size_t)rIdx[i][m] * DIM + d0);
        float wx = 0.f, wy = 0.f, wz = 0.f, ww = 0.f;
        #pragma unroll
        for (int m = 0; m < 8; ++m) {
            float c = csum[i][m];
            wx += c * b2f(va[m].x); wy += c * b2f(va[m].y);
            wz += c * b2f(va[m].z); ww += c * b2f(va[m].w);
        }
        // batch 2: remaining 7 VT rows
        ushort4 vb[7];
        #pragma unroll
        for (int m = 0; m < 7; ++m)
            vb[m] = *(const ushort4*)(VT16 + (size_t)rIdx[i][8 + m] * DIM + d0);
        #pragma unroll
        for (int m = 0; m < 7; ++m) {
            float c = csum[i][8 + m];
            wx += c * b2f(vb[m].x); wy += c * b2f(vb[m].y);
            wz += c * b2f(vb[m].z); ww += c * b2f(vb[m].w);
        }
        float4 res;
        res.x = 2.f * wx + b2f(ve.x) + b2f(se.x);
        res.y = 2.f * wy + b2f(ve.y) + b2f(se.y);
        res.z = 2.f * wz + b2f(ve.z) + b2f(se.z);
        res.w = 2.f * ww + b2f(ve.w) + b2f(se.w);
        *(float4*)&out[(size_t)n * DIM + d0] = res;
    }
}

extern "C" void kernel_launch(void* const* d_in, const int* in_sizes, int n_in,
                              void* d_out, int out_size, void* d_ws, size_t ws_size,
                              hipStream_t stream)
{
    const int*   words      = (const int*)d_in[0];
    const int*   rowsI      = (const int*)d_in[1];
    const int*   colsI      = (const int*)d_in[2];
    const int*   dirsI      = (const int*)d_in[3];
    const int*   scoresI    = (const int*)d_in[4];
    const float* letter_emb = (const float*)d_in[5];
    const float* positional = (const float*)d_in[6];
    const float* Wq         = (const float*)d_in[7];
    const float* bq         = (const float*)d_in[8];
    const float* Wk         = (const float*)d_in[9];
    const float* bk         = (const float*)d_in[10];
    const float* Wv         = (const float*)d_in[11];
    const float* bv         = (const float*)d_in[12];
    const float* row_emb    = (const float*)d_in[13];
    const float* col_emb    = (const float*)d_in[14];
    const float* dir_emb    = (const float*)d_in[15];
    const float* score_emb  = (const float*)d_in[16];
    float* out = (float*)d_out;

    // workspace: QT f32 | KT f32 | H f2[405*408] | VT bf16[405*256] | EP2 bf16[550*256]
    float*  QT = (float*)d_ws;
    float*  KT = QT + NR * DIM;
    float2* Hm = (float2*)(KT + NR * DIM);
    __hip_bfloat16* VT  = (__hip_bfloat16*)((char*)Hm + (size_t)NR * GSH * sizeof(float2));
    __hip_bfloat16* EP2 = VT + (size_t)NR * DIM;

    qkv_gemm<<<1386, 256, 0, stream>>>(letter_emb, positional, Wq, bq, Wk, bk,
                                       Wv, bv, row_emb, col_emb, dir_emb,
                                       score_emb, QT, KT, VT, EP2);
    h_matrix<<<351, 256, 0, stream>>>(QT, KT, Hm);
    moves_kernel<<<NMOV / MPB, 256, 0, stream>>>(words, rowsI, colsI, dirsI,
                                                 scoresI, Hm, VT, EP2, out);
}

// Round 13
// 57.225 us; speedup vs baseline: 1.3030x; 1.0582x over previous
//
#include <hip/hip_runtime.h>
#include <hip/hip_bf16.h>

#define NMOV 32768
#define LW 15
#define DIM 256
#define NVOC 27
#define NR 405       // NVOC * LW distinct (letter, position) rows
#define GSH 408      // row stride of H in float2 units
#define MPB 16       // moves per block in moves_kernel
#define NEP 550      // EP2 rows: 450 vec combos + 100 score rows

__device__ __forceinline__ float b2f(unsigned short u) {
    return __uint_as_float(((unsigned int)u) << 16);
}
__device__ __forceinline__ unsigned short f2bu(float x) {
    __hip_bfloat16 h = __float2bfloat16(x);
    return *reinterpret_cast<unsigned short*>(&h);
}

// pair index p -> (l<<4 | m), l >= m, p = l(l+1)/2 + m
__device__ const unsigned char PAIR_LUT[120] = {
    0x00,
    0x10,0x11,
    0x20,0x21,0x22,
    0x30,0x31,0x32,0x33,
    0x40,0x41,0x42,0x43,0x44,
    0x50,0x51,0x52,0x53,0x54,0x55,
    0x60,0x61,0x62,0x63,0x64,0x65,0x66,
    0x70,0x71,0x72,0x73,0x74,0x75,0x76,0x77,
    0x80,0x81,0x82,0x83,0x84,0x85,0x86,0x87,0x88,
    0x90,0x91,0x92,0x93,0x94,0x95,0x96,0x97,0x98,0x99,
    0xA0,0xA1,0xA2,0xA3,0xA4,0xA5,0xA6,0xA7,0xA8,0xA9,0xAA,
    0xB0,0xB1,0xB2,0xB3,0xB4,0xB5,0xB6,0xB7,0xB8,0xB9,0xBA,0xBB,
    0xC0,0xC1,0xC2,0xC3,0xC4,0xC5,0xC6,0xC7,0xC8,0xC9,0xCA,0xCB,0xCC,
    0xD0,0xD1,0xD2,0xD3,0xD4,0xD5,0xD6,0xD7,0xD8,0xD9,0xDA,0xDB,0xDC,0xDD,
    0xE0,0xE1,0xE2,0xE3,0xE4,0xE5,0xE6,0xE7,0xE8,0xE9,0xEA,0xEB,0xEC,0xED,0xEE
};

// ---------------------------------------------------------------------------
// Kernel 1 (unchanged from R12): 16x16-tile QKV GEMM + EP2 builder.
// ---------------------------------------------------------------------------
__global__ __launch_bounds__(256) void qkv_gemm(
    const float* __restrict__ le, const float* __restrict__ pos,
    const float* __restrict__ Wq, const float* __restrict__ bq,
    const float* __restrict__ Wk, const float* __restrict__ bk,
    const float* __restrict__ Wv, const float* __restrict__ bv,
    const float* __restrict__ row_emb, const float* __restrict__ col_emb,
    const float* __restrict__ dir_emb, const float* __restrict__ score_emb,
    float* __restrict__ QT, float* __restrict__ KT,
    __hip_bfloat16* __restrict__ VT, __hip_bfloat16* __restrict__ EP2)
{
    const int t = threadIdx.x;
    if (blockIdx.x >= 1248) {
        int idx = (blockIdx.x - 1248) * 1024 + t * 4;   // 4 elems, same row
        if (idx < NEP * DIM) {
            int v = idx >> 8, dcol = idx & 255;
            float4 s4;
            if (v < 450) {
                int r = v / 30, rm = v % 30, c = rm >> 1, d = rm & 1;
                float4 a = *(const float4*)&row_emb[r * DIM + dcol];
                float4 b = *(const float4*)&col_emb[c * DIM + dcol];
                float4 e = *(const float4*)&dir_emb[d * DIM + dcol];
                s4 = make_float4(a.x + b.x + e.x, a.y + b.y + e.y,
                                 a.z + b.z + e.z, a.w + b.w + e.w);
            } else {
                s4 = *(const float4*)&score_emb[(v - 450) * DIM + dcol];
            }
            ushort4 o;
            o.x = f2bu(s4.x); o.y = f2bu(s4.y);
            o.z = f2bu(s4.z); o.w = f2bu(s4.w);
            *(ushort4*)((unsigned short*)EP2 + idx) = o;
        }
        return;
    }

    __shared__ float Ash[16][260];
    __shared__ float Bsh[16][260];
    const int bx = blockIdx.x % 48;
    const int by = blockIdx.x / 48;
    const int r0 = by * 16;
    const int mat = bx >> 4;             // 0=Q 1=K 2=V
    const int nb  = (bx & 15) * 16;      // col base within mat
    const float* W  = (mat == 0) ? Wq : (mat == 1) ? Wk : Wv;
    const float* bb = (mat == 0) ? bq : (mat == 1) ? bk : bv;

    #pragma unroll
    for (int s = 0; s < 4; ++s) {
        int slot = s * 256 + t;          // 1024 float4 slots per tile
        int row = slot >> 6, q4 = slot & 63;
        int r = r0 + row;
        float4 va = make_float4(0.f, 0.f, 0.f, 0.f);
        if (r < NR) {
            int c = r / 15, l = r - c * 15;
            float4 lv = *(const float4*)&le[c * DIM + q4 * 4];
            float4 pv = *(const float4*)&pos[l * DIM + q4 * 4];
            va = make_float4(lv.x + pv.x, lv.y + pv.y, lv.z + pv.z, lv.w + pv.w);
        }
        *(float4*)&Ash[row][q4 * 4] = va;
        float4 vb = *(const float4*)&W[(nb + row) * DIM + q4 * 4];
        *(float4*)&Bsh[row][q4 * 4] = vb;
    }
    __syncthreads();

    const int tj = t & 15, ti = t >> 4;
    float acc = 0.f;
    #pragma unroll 8
    for (int k = 0; k < DIM; k += 4) {
        float4 a = *(const float4*)&Ash[ti][k];
        float4 b = *(const float4*)&Bsh[tj][k];
        acc += a.x * b.x + a.y * b.y + a.z * b.z + a.w * b.w;
    }

    const int r = r0 + ti;
    if (r < NR) {
        float v = acc + bb[nb + tj];
        int dcol = nb + tj;
        if (mat == 0)      QT[r * DIM + dcol] = v;
        else if (mat == 1) KT[r * DIM + dcol] = v;
        else               VT[r * DIM + dcol] = __float2bfloat16(v);
    }
}

// ---------------------------------------------------------------------------
// Kernel 2 v4: UNPAIRED H tiles for load balance. 26x26 = 676 blocks
// (2.64/CU vs 351 = 1.37/CU with 2x-heavy blocks -> straggler CUs).
// Block (bi,bj) computes g(i,j) for its 16x16 tile and writes
//   H[i][j].x = g(i,j)            (row-coalesced, 2 lines / 16 lanes)
//   H[j][i].y = g(i,j) = G[i][j]  (via LDS transpose, same coalescing)
// Fields are disjoint across blocks; diagonal writes .x/.y once each.
// LDS 9.8KB (was 17.4), per-block work halved.
// ---------------------------------------------------------------------------
__global__ __launch_bounds__(256) void h_matrix(
    const float* __restrict__ QT, const float* __restrict__ KT,
    float2* __restrict__ H)
{
    __shared__ float Qs[16][68], Ks[16][68], Ts[16][17];
    const int bi = blockIdx.x / 26, bj = blockIdx.x % 26;
    const int i0 = bi * 16, j0 = bj * 16;
    const int t = threadIdx.x;
    const int ti = t >> 4, tj = t & 15;

    float acc = 0.f;
    for (int k0 = 0; k0 < DIM; k0 += 64) {
        #pragma unroll
        for (int s = 0; s < 2; ++s) {
            int lin = s * 256 + t;           // 512 float4 slots
            int tile = lin >> 8;             // 0=Q 1=K
            int r    = (lin >> 4) & 15;
            int c4   = lin & 15;
            int grow = tile ? (j0 + r) : (i0 + r);
            const float* src = tile ? KT : QT;
            float4 v = (grow < NR)
                ? *(const float4*)&src[grow * DIM + k0 + c4 * 4]
                : make_float4(0.f, 0.f, 0.f, 0.f);
            float* dst = tile ? &Ks[r][c4 * 4] : &Qs[r][c4 * 4];
            *(float4*)dst = v;
        }
        __syncthreads();
        #pragma unroll 4
        for (int k = 0; k < 64; k += 4) {
            float4 q = *(const float4*)&Qs[ti][k];
            float4 kk = *(const float4*)&Ks[tj][k];
            acc += q.x * kk.x + q.y * kk.y + q.z * kk.z + q.w * kk.w;
        }
        __syncthreads();
    }

    // direct store: H[i][j].x
    const int i1 = i0 + ti, j1 = j0 + tj;
    if (i1 < NR && j1 < NR) ((float*)&H[i1 * GSH + j1])[0] = acc;

    // transposed store: H[j][i].y = G[i][j]
    Ts[ti][tj] = acc;
    __syncthreads();
    const float tr = Ts[tj][ti];             // = g(i0+tj, j0+ti)
    const int j2 = j0 + ti, i2 = i0 + tj;    // store row j0+ti, col i0+tj
    if (j2 < NR && i2 < NR) ((float*)&H[j2 * GSH + i2])[1] = tr;
}

// ---------------------------------------------------------------------------
// Kernel 3 (R12 base, phase-2 unroll 2): wave-synchronous, ZERO __syncthreads.
// unroll 2 doubles phase-2 loads in flight (~20 per wait). VGPR budget:
// ~55-62, must stay under the 64 cliff (R11 lesson).
// NOTE: __launch_bounds__(256) ONLY — a min-waves arg spills to scratch (R4).
// ---------------------------------------------------------------------------
__global__ __launch_bounds__(256) void moves_kernel(
    const int* __restrict__ words, const int* __restrict__ rowsI,
    const int* __restrict__ colsI, const int* __restrict__ dirsI,
    const int* __restrict__ scoresI,
    const float2* __restrict__ H, const __hip_bfloat16* __restrict__ VT,
    const __hip_bfloat16* __restrict__ EP2,
    float* __restrict__ out)
{
    __shared__ float S[MPB][LW][17];     // 15x15 score matrix per move (padded)
    __shared__ int   rIdx[MPB][16];      // row indices per move
    __shared__ float csum[MPB][16];      // per-move column sums
    __shared__ int   meta[MPB][2];       // EP2 row indices: vec, score
    const int base = blockIdx.x * MPB;
    const int t  = threadIdx.x;
    const int w  = t >> 6;               // wave id: owns moves 4w..4w+3
    const int ln = t & 63;
    const int hw = t >> 5;               // half-wave: owns moves 2hw, 2hw+1
    const int j  = t & 31;

    // rIdx + meta loaded by the OWNING wave's lanes (wave-local LDS)
    if (ln < 60) {
        int mvl = ln / 15, row = ln - mvl * 15;
        int mv = w * 4 + mvl;
        rIdx[mv][row] = words[(base + mv) * LW + row] * LW + row;
    }
    if (ln < 8) {
        int mvl = ln >> 1, f = ln & 1;
        int n = base + w * 4 + mvl;
        int v = (f == 0) ? (rowsI[n] * 30 + colsI[n] * 2 + dirsI[n])
                         : (450 + min(scoresI[n], 99));
        meta[w * 4 + mvl][f] = v;
    }
    __builtin_amdgcn_wave_barrier();

    // -------- phase 1: 8 H-gathers in flight per wave (2 moves x 4 pairs)
    const int mv0 = hw * 2, mv1 = mv0 + 1;
    float2 h0[4], h1[4];
    int ll[4], mm[4];
    #pragma unroll
    for (int k = 0; k < 4; ++k) {
        int p = j + 32 * k;
        if (p < 120) {
            int lm = PAIR_LUT[p];
            ll[k] = lm >> 4; mm[k] = lm & 15;
            h0[k] = H[(size_t)rIdx[mv0][ll[k]] * GSH + rIdx[mv0][mm[k]]];
            h1[k] = H[(size_t)rIdx[mv1][ll[k]] * GSH + rIdx[mv1][mm[k]]];
        }
    }
    #pragma unroll
    for (int k = 0; k < 4; ++k) {
        int p = j + 32 * k;
        if (p < 120) {
            S[mv0][ll[k]][mm[k]] = h0[k].x;
            S[mv0][mm[k]][ll[k]] = h0[k].y;
            S[mv1][ll[k]][mm[k]] = h1[k].x;
            S[mv1][mm[k]][ll[k]] = h1[k].y;
        }
    }
    __builtin_amdgcn_wave_barrier();

    // -------- row softmax: lane ln<60 -> (move w*4 + ln/15, row ln%15)
    if (ln < 60) {
        int mvl = ln / 15, row = ln - mvl * 15;
        int mv = w * 4 + mvl;
        float s[LW];
        #pragma unroll
        for (int m = 0; m < LW; ++m) s[m] = S[mv][row][m];
        float mx = s[0];
        #pragma unroll
        for (int m = 1; m < LW; ++m) mx = fmaxf(mx, s[m]);
        float sum = 0.f;
        #pragma unroll
        for (int m = 0; m < LW; ++m) { s[m] = __expf(s[m] - mx); sum += s[m]; }
        float inv = 1.0f / sum;
        #pragma unroll
        for (int m = 0; m < LW; ++m) S[mv][row][m] = s[m] * inv;
    }
    __builtin_amdgcn_wave_barrier();

    // -------- column sums: lane ln<60 -> (move, column)
    if (ln < 60) {
        int mvl = ln / 15, col = ln - mvl * 15;
        int mv = w * 4 + mvl;
        float acc = 0.f;
        #pragma unroll
        for (int l = 0; l < LW; ++l) acc += S[mv][l][col];
        csum[mv][col] = acc;
    }
    __builtin_amdgcn_wave_barrier();

    // -------- phase 2: wave w handles moves 4w..4w+3, two at a time
    const int d0 = ln * 4;
    const unsigned short* VT16 = (const unsigned short*)VT;
    const unsigned short* EP16 = (const unsigned short*)EP2;
    #pragma unroll 2
    for (int s2 = 0; s2 < 4; ++s2) {
        const int i = w * 4 + s2;
        const int n = base + i;
        // batch 1: 2 bf16 epilogue rows + first 8 VT rows
        ushort4 ve = *(const ushort4*)(EP16 + meta[i][0] * DIM + d0);
        ushort4 se = *(const ushort4*)(EP16 + meta[i][1] * DIM + d0);
        ushort4 va[8];
        #pragma unroll
        for (int m = 0; m < 8; ++m)
            va[m] = *(const ushort4*)(VT16 + (size_t)rIdx[i][m] * DIM + d0);
        float wx = 0.f, wy = 0.f, wz = 0.f, ww = 0.f;
        #pragma unroll
        for (int m = 0; m < 8; ++m) {
            float c = csum[i][m];
            wx += c * b2f(va[m].x); wy += c * b2f(va[m].y);
            wz += c * b2f(va[m].z); ww += c * b2f(va[m].w);
        }
        // batch 2: remaining 7 VT rows
        ushort4 vb[7];
        #pragma unroll
        for (int m = 0; m < 7; ++m)
            vb[m] = *(const ushort4*)(VT16 + (size_t)rIdx[i][8 + m] * DIM + d0);
        #pragma unroll
        for (int m = 0; m < 7; ++m) {
            float c = csum[i][8 + m];
            wx += c * b2f(vb[m].x); wy += c * b2f(vb[m].y);
            wz += c * b2f(vb[m].z); ww += c * b2f(vb[m].w);
        }
        float4 res;
        res.x = 2.f * wx + b2f(ve.x) + b2f(se.x);
        res.y = 2.f * wy + b2f(ve.y) + b2f(se.y);
        res.z = 2.f * wz + b2f(ve.z) + b2f(se.z);
        res.w = 2.f * ww + b2f(ve.w) + b2f(se.w);
        *(float4*)&out[(size_t)n * DIM + d0] = res;
    }
}

extern "C" void kernel_launch(void* const* d_in, const int* in_sizes, int n_in,
                              void* d_out, int out_size, void* d_ws, size_t ws_size,
                              hipStream_t stream)
{
    const int*   words      = (const int*)d_in[0];
    const int*   rowsI      = (const int*)d_in[1];
    const int*   colsI      = (const int*)d_in[2];
    const int*   dirsI      = (const int*)d_in[3];
    const int*   scoresI    = (const int*)d_in[4];
    const float* letter_emb = (const float*)d_in[5];
    const float* positional = (const float*)d_in[6];
    const float* Wq         = (const float*)d_in[7];
    const float* bq         = (const float*)d_in[8];
    const float* Wk         = (const float*)d_in[9];
    const float* bk         = (const float*)d_in[10];
    const float* Wv         = (const float*)d_in[11];
    const float* bv         = (const float*)d_in[12];
    const float* row_emb    = (const float*)d_in[13];
    const float* col_emb    = (const float*)d_in[14];
    const float* dir_emb    = (const float*)d_in[15];
    const float* score_emb  = (const float*)d_in[16];
    float* out = (float*)d_out;

    // workspace: QT f32 | KT f32 | H f2[405*408] | VT bf16[405*256] | EP2 bf16[550*256]
    float*  QT = (float*)d_ws;
    float*  KT = QT + NR * DIM;
    float2* Hm = (float2*)(KT + NR * DIM);
    __hip_bfloat16* VT  = (__hip_bfloat16*)((char*)Hm + (size_t)NR * GSH * sizeof(float2));
    __hip_bfloat16* EP2 = VT + (size_t)NR * DIM;

    qkv_gemm<<<1386, 256, 0, stream>>>(letter_emb, positional, Wq, bq, Wk, bk,
                                       Wv, bv, row_emb, col_emb, dir_emb,
                                       score_emb, QT, KT, VT, EP2);
    h_matrix<<<676, 256, 0, stream>>>(QT, KT, Hm);
    moves_kernel<<<NMOV / MPB, 256, 0, stream>>>(words, rowsI, colsI, dirsI,
                                                 scoresI, Hm, VT, EP2, out);
}